// Round 7
// baseline (340.839 us; speedup 1.0000x reference)
//
#include <hip/hip_runtime.h>

typedef unsigned int u32;
typedef _Float16 v2h __attribute__((ext_vector_type(2)));
typedef __fp16   v2fp __attribute__((ext_vector_type(2)));

#define E_TOT 160000
#define TPB   256
#define NBLK  1250        // (E/256)=625 tiles x 2 classes
#define ARENA 27          // u32/thread: xp[0..8] | hp[9..25] (17) | pad
#define SBROWS 51         // SoA rows: s1T[0..23] (s1T[q*8+i]=s1[i*3+q]) | Bv[24..50]
// ws (u32, f16-pairs): [p(0,0):0..1920) [p(1,0):1920..3840) [p(0,1):3840..5760) [p(1,1):5760..9856)
// per p<3 pair: W1p[9][32]@+0 | W2p[17][32]@+288 | W3p[34 rows][32 cp]@+832   (rows 32=b3,33=0)
// p3 pair:      W1p@+0 | W2p@+288 | W3p[17 mp][192 c]@+832                     (mp16=(b3,0))
// Weights read DIRECTLY from global ws with wave-uniform addresses -> s_load
// into SGPRs (one fetch per wave, scalar pipe); v_dot2 takes SGPR src0.
// R7: kill the class-B register spill BY CONSTRUCTION (R1/R5/R6 all spilled
// ~48 dwords/thread -> +30MB dirty WRITE; allocator knobs were no-ops 3x).
// s1 (transposed) and Bv live in an LDS SoA array SB[51][TPB] (per-lane
// columns, conflict-free b32, LDS pipe is otherwise idle); msg1 buffered in
// regs and burst-written as 6 x float4 (also kills partial-line drains).
// Class-B live set ~80 static regs. LDS 79.9KB -> 2 blocks/CU (8 waves).

#if __has_builtin(__builtin_amdgcn_fdot2)
__device__ __forceinline__ float FDOT2(v2h a, v2h b, float c){
  return __builtin_amdgcn_fdot2(a, b, c, false);
}
#else
__device__ __forceinline__ float FDOT2(v2h a, v2h b, float c){
  return fmaf((float)a[0], (float)b[0], fmaf((float)a[1], (float)b[1], c));
}
#endif

__device__ __forceinline__ u32 pkh(float a, float b){
  union { v2fp h; u32 x; } u;
  u.h = __builtin_amdgcn_cvt_pkrtz(a, b);
  return u.x;
}
__device__ __forceinline__ v2h asvh(u32 x){
  union { u32 x; v2h h; } u; u.x = x; return u.h;
}

struct WPtrs { const float* p[24]; };  // pair order (0,0),(1,0),(0,1),(1,1) x {w1,b1,w2,b2,w3,b3}

__global__ __launch_bounds__(256) void prep_kernel(WPtrs S, u32* __restrict__ ws)
{
  const int t = blockIdx.x * 256 + threadIdx.x;
  if (t >= 9856) return;
  int pair, rel;
  if (t < 5760){ pair = t / 1920; rel = t % 1920; }
  else         { pair = 3;        rel = t - 5760; }
  const float* __restrict__ w1 = S.p[pair*6+0];
  const float* __restrict__ b1 = S.p[pair*6+1];
  const float* __restrict__ w2 = S.p[pair*6+2];
  const float* __restrict__ b2 = S.p[pair*6+3];
  const float* __restrict__ w3 = S.p[pair*6+4];
  const float* __restrict__ b3 = S.p[pair*6+5];
  float a, b;
  if (rel < 288){                       // W1p: k-pairs, row 8 pairs (w1[16], b1)
    int kp = rel >> 5, m = rel & 31;
    a = w1[2*kp*32 + m];
    b = (2*kp+1 < 17) ? w1[(2*kp+1)*32 + m] : b1[m];
  } else if (rel < 832){                // W2p: k-pairs, row 16 = (b2, 0)
    int j = rel - 288, kp = j >> 5, m = j & 31;
    if (kp < 16){ a = w2[2*kp*32 + m]; b = w2[(2*kp+1)*32 + m]; }
    else        { a = b2[m];           b = 0.f; }
  } else if (pair < 3){                 // W3p34: c-pairs, rows 32=b3,33=0
    int j = rel - 832, r = j >> 5, cp = j & 31;
    if      (r < 32){ a = w3[r*64 + 2*cp]; b = w3[r*64 + 2*cp + 1]; }
    else if (r ==32){ a = b3[2*cp];        b = b3[2*cp + 1]; }
    else            { a = 0.f;             b = 0.f; }
  } else {                              // W3p17: m-pairs, mp16 = (b3, 0)
    int j = rel - 832, mp = j / 192, c = j % 192;
    if (mp < 16){ a = w3[2*mp*192 + c]; b = w3[(2*mp+1)*192 + c]; }
    else        { a = b3[c];            b = 0.f; }
  }
  ws[t] = pkh(a, b);
}

// radial MLP: xp in A[0..8], hp (h1 then h2) in A[9..24], A[25]=(1,0) const
// W is the GLOBAL ws buffer; pb is a global u32 base (wave-uniform -> s_load)
__device__ __forceinline__ void mlp(const u32* __restrict__ W, int pb, u32* __restrict__ A)
{
  float g[32];
  #pragma unroll
  for (int m = 0; m < 32; ++m) g[m] = 0.f;
  #pragma unroll 1
  for (int kp = 0; kp < 9; ++kp){
    v2h x = asvh(A[kp]);
    const uint4* __restrict__ r4 = (const uint4*)(W + pb + kp*32);
    #pragma unroll
    for (int j = 0; j < 8; ++j){
      uint4 w = r4[j];                               // s_load_dwordx4 (uniform)
      g[4*j+0] = FDOT2(asvh(w.x), x, g[4*j+0]);
      g[4*j+1] = FDOT2(asvh(w.y), x, g[4*j+1]);
      g[4*j+2] = FDOT2(asvh(w.z), x, g[4*j+2]);
      g[4*j+3] = FDOT2(asvh(w.w), x, g[4*j+3]);
    }
  }
  #pragma unroll
  for (int j = 0; j < 16; ++j)
    A[9+j] = pkh(fmaxf(g[2*j], 0.f), fmaxf(g[2*j+1], 0.f));
  float g2[32];
  #pragma unroll
  for (int m = 0; m < 32; ++m) g2[m] = 0.f;
  #pragma unroll 1
  for (int kp = 0; kp < 17; ++kp){                   // kp=16 reads A[25]=(1,0) -> +b2
    v2h x = asvh(A[9+kp]);
    const uint4* __restrict__ r4 = (const uint4*)(W + pb + 288 + kp*32);
    #pragma unroll
    for (int j = 0; j < 8; ++j){
      uint4 w = r4[j];
      g2[4*j+0] = FDOT2(asvh(w.x), x, g2[4*j+0]);
      g2[4*j+1] = FDOT2(asvh(w.y), x, g2[4*j+1]);
      g2[4*j+2] = FDOT2(asvh(w.z), x, g2[4*j+2]);
      g2[4*j+3] = FDOT2(asvh(w.w), x, g2[4*j+3]);
    }
  }
  #pragma unroll
  for (int j = 0; j < 16; ++j)
    A[9+j] = pkh(fmaxf(g2[2*j], 0.f), fmaxf(g2[2*j+1], 0.f));
}

// layer3, 64 cols (c-paired): acc[o] = sum_rows h_r * (w3row . v), bias via rows 32/33
__device__ __forceinline__ void l3a(const u32* __restrict__ W, int wb,
                                    const u32* __restrict__ A,
                                    const u32 (&vp)[4], float (&acc)[8])
{
  #pragma unroll
  for (int o = 0; o < 8; ++o) acc[o] = 0.f;
  #pragma unroll 1
  for (int mp = 0; mp < 17; ++mp){
    v2h hp = asvh(A[9+mp]);
    float h0 = (float)hp[0], h1 = (float)hp[1];
    const uint4* __restrict__ rA = (const uint4*)(W + wb + (2*mp)*32);
    const uint4* __restrict__ rB = rA + 8;
    #pragma unroll
    for (int o = 0; o < 8; ++o){
      uint4 wa = rA[o];                              // s_load (uniform)
      uint4 wb2 = rB[o];
      float tA = 0.f, tB = 0.f;
      tA = FDOT2(asvh(wa.x), asvh(vp[0]), tA);
      tA = FDOT2(asvh(wa.y), asvh(vp[1]), tA);
      tA = FDOT2(asvh(wa.z), asvh(vp[2]), tA);
      tA = FDOT2(asvh(wa.w), asvh(vp[3]), tA);
      tB = FDOT2(asvh(wb2.x), asvh(vp[0]), tB);
      tB = FDOT2(asvh(wb2.y), asvh(vp[1]), tB);
      tB = FDOT2(asvh(wb2.z), asvh(vp[2]), tB);
      tB = FDOT2(asvh(wb2.w), asvh(vp[3]), tB);
      acc[o] = fmaf(h0, tA, fmaf(h1, tB, acc[o]));
    }
  }
}

__global__ __launch_bounds__(TPB, 2) void edge_kernel(
    const float* __restrict__ feat0, const float* __restrict__ feat1,
    const float* __restrict__ wE,    const float* __restrict__ radial,
    const float* __restrict__ b00,   const float* __restrict__ b01,
    const float* __restrict__ b10,   const float* __restrict__ b11,
    const int* __restrict__ src_idx, const u32* __restrict__ ws,
    float* __restrict__ out)
{
  __shared__ u32 AR[TPB * ARENA];      // per-thread arena (27.6 KB)
  __shared__ u32 SB[SBROWS * TPB];     // class-B s1T/Bv SoA (52.2 KB)
  const int tid = threadIdx.x;
  const int cls = blockIdx.x & 1;
  const int e   = (blockIdx.x >> 1) * TPB + tid;
  u32* A = AR + tid * ARENA;

  // edge features -> f16 pairs in arena
  {
    const float4* wp = (const float4*)(wE + (size_t)e * 16);
    float4 a = wp[0], b = wp[1], c = wp[2], d = wp[3];
    A[0] = pkh(a.x, a.y); A[1] = pkh(a.z, a.w);
    A[2] = pkh(b.x, b.y); A[3] = pkh(b.z, b.w);
    A[4] = pkh(c.x, c.y); A[5] = pkh(c.z, c.w);
    A[6] = pkh(d.x, d.y); A[7] = pkh(d.z, d.w);
    A[8] = pkh(radial[e], 1.0f);      // pairs with (w1[16], b1) row
    A[25] = pkh(1.0f, 0.0f);          // constant (1,0) bias selector
  }
  const int idx = src_idx[e];
  // no __syncthreads needed — arena/SB columns are strictly per-thread

  if (cls == 0){
    // ================= class A: pairs (0,0) + (1,0) -> out0 =================
    const float bB = b00[e];
    float B10[3];
    #pragma unroll
    for (int q = 0; q < 3; ++q) B10[q] = b10[(size_t)e*3 + q];
    u32 vp0[4], vp2[4];
    {
      const float4* f0 = (const float4*)(feat0 + (size_t)idx * 8);
      float4 a = f0[0], b = f0[1];
      vp0[0] = pkh(a.x, a.y); vp0[1] = pkh(a.z, a.w);
      vp0[2] = pkh(b.x, b.y); vp0[3] = pkh(b.z, b.w);
      const float4* f1 = (const float4*)(feat1 + (size_t)idx * 24);
      float s1[24];
      #pragma unroll
      for (int j = 0; j < 6; ++j){
        float4 v = f1[j];
        s1[4*j+0]=v.x; s1[4*j+1]=v.y; s1[4*j+2]=v.z; s1[4*j+3]=v.w;
      }
      float Uv[8];
      #pragma unroll
      for (int i = 0; i < 8; ++i)
        Uv[i] = fmaf(B10[0], s1[3*i+0], fmaf(B10[1], s1[3*i+1], B10[2]*s1[3*i+2]));
      #pragma unroll
      for (int j = 0; j < 4; ++j) vp2[j] = pkh(Uv[2*j], Uv[2*j+1]);
    }
    float msg0[8], acc[8];
    mlp(ws, 0, A);                       // pair (0,0)
    l3a(ws, 832, A, vp0, acc);
    #pragma unroll
    for (int o = 0; o < 8; ++o) msg0[o] = acc[o] * bB;
    mlp(ws, 1920, A);                    // pair (1,0)
    l3a(ws, 1920 + 832, A, vp2, acc);
    #pragma unroll
    for (int o = 0; o < 8; ++o) msg0[o] += acc[o];
    float* o0 = out + (size_t)e * 8;
    ((float4*)o0)[0] = make_float4(msg0[0], msg0[1], msg0[2], msg0[3]);
    ((float4*)o0)[1] = make_float4(msg0[4], msg0[5], msg0[6], msg0[7]);
  } else {
    // ================= class B: pairs (0,1) + (1,1) -> out1 =================
    float B01[3];
    #pragma unroll
    for (int q = 0; q < 3; ++q) B01[q] = b01[(size_t)e*3 + q];
    u32 vp0[4];
    {
      const float4* f0 = (const float4*)(feat0 + (size_t)idx * 8);
      float4 a = f0[0], b = f0[1];
      vp0[0] = pkh(a.x, a.y); vp0[1] = pkh(a.z, a.w);
      vp0[2] = pkh(b.x, b.y); vp0[3] = pkh(b.z, b.w);
      // s1 -> LDS transposed: SB row q*8+i holds s1[i*3+q] (per-lane column)
      const float4* f1 = (const float4*)(feat1 + (size_t)idx * 24);
      float s1[24];
      #pragma unroll
      for (int j = 0; j < 6; ++j){
        float4 v = f1[j];
        s1[4*j+0]=v.x; s1[4*j+1]=v.y; s1[4*j+2]=v.z; s1[4*j+3]=v.w;
      }
      #pragma unroll
      for (int i = 0; i < 8; ++i)
        #pragma unroll
        for (int q = 0; q < 3; ++q)
          SB[(q*8 + i)*TPB + tid] = __float_as_uint(s1[i*3 + q]);
    }
    float t01[8];
    mlp(ws, 3840, A);                    // pair (0,1)
    l3a(ws, 3840 + 832, A, vp0, t01);
    {
      // Bv -> LDS rows 24..50 (no register copy held across the o-loop)
      const float* __restrict__ bp = b11 + (size_t)e * 27;
      #pragma unroll
      for (int j = 0; j < 27; ++j)
        SB[(24 + j)*TPB + tid] = __float_as_uint(bp[j]);
    }
    mlp(ws, 5760, A);                    // pair (1,1)
    float msg1[24];
    #pragma unroll 1
    for (int o = 0; o < 8; ++o){
      float a24[24];
      #pragma unroll
      for (int c = 0; c < 24; ++c) a24[c] = 0.f;
      #pragma unroll 1
      for (int mp = 0; mp < 17; ++mp){   // mp16 row = (b3,0) with hp=(1,0)
        v2h hp = asvh(A[9+mp]);
        const uint4* __restrict__ seg = (const uint4*)(ws + 5760 + 832 + mp*192 + o*24);
        #pragma unroll
        for (int j4 = 0; j4 < 6; ++j4){
          uint4 w = seg[j4];             // s_load (uniform)
          a24[4*j4+0] = FDOT2(asvh(w.x), hp, a24[4*j4+0]);
          a24[4*j4+1] = FDOT2(asvh(w.y), hp, a24[4*j4+1]);
          a24[4*j4+2] = FDOT2(asvh(w.z), hp, a24[4*j4+2]);
          a24[4*j4+3] = FDOT2(asvh(w.w), hp, a24[4*j4+3]);
        }
      }
      float D[9];                        // D[q,f] = sum_i R[o,i,f]*s1[i,q]
      #pragma unroll
      for (int q = 0; q < 3; ++q){
        float sc[8];
        #pragma unroll
        for (int i = 0; i < 8; ++i)
          sc[i] = __uint_as_float(SB[(q*8 + i)*TPB + tid]);  // ds_read_b32
        #pragma unroll
        for (int f = 0; f < 3; ++f){
          float t = 0.f;
          #pragma unroll
          for (int i = 0; i < 8; ++i) t = fmaf(a24[i*3+f], sc[i], t);
          D[q*3+f] = t;
        }
      }
      #pragma unroll
      for (int p = 0; p < 3; ++p){
        float t = t01[o] * B01[p];
        #pragma unroll
        for (int q = 0; q < 3; ++q){
          #pragma unroll
          for (int f = 0; f < 3; ++f)
            t = fmaf(__uint_as_float(SB[(24 + p*9 + q*3 + f)*TPB + tid]),
                     D[q*3+f], t);
        }
        msg1[o*3 + p] = t;
      }
    }
    float* o1 = out + (size_t)E_TOT * 8 + (size_t)e * 24;
    #pragma unroll
    for (int j = 0; j < 6; ++j)
      ((float4*)o1)[j] = make_float4(msg1[4*j+0], msg1[4*j+1], msg1[4*j+2], msg1[4*j+3]);
  }
}

extern "C" void kernel_launch(void* const* d_in, const int* in_sizes, int n_in,
                              void* d_out, int out_size, void* d_ws, size_t ws_size,
                              hipStream_t stream)
{
  const float* feat0 = (const float*)d_in[0];
  const float* feat1 = (const float*)d_in[1];
  const float* wE    = (const float*)d_in[2];
  const float* rad   = (const float*)d_in[3];
  const float* b00   = (const float*)d_in[4];
  const float* b01   = (const float*)d_in[11];
  const float* b10   = (const float*)d_in[18];
  const float* b11   = (const float*)d_in[25];
  const int* sidx    = (const int*)d_in[32];
  u32* ws            = (u32*)d_ws;

  // ws pair order: (0,0), (1,0), (0,1), (1,1)  -> d_in weight bases 5, 19, 12, 26
  const int base[4] = {5, 19, 12, 26};
  WPtrs S;
  for (int p = 0; p < 4; ++p)
    for (int k = 0; k < 6; ++k)
      S.p[p*6 + k] = (const float*)d_in[base[p] + k];

  prep_kernel<<<39, 256, 0, stream>>>(S, ws);
  edge_kernel<<<NBLK, TPB, 0, stream>>>(feat0, feat1, wE, rad, b00, b01, b10, b11,
                                        sidx, ws, (float*)d_out);
}

// Round 8
// 170.507 us; speedup vs baseline: 1.9990x; 1.9990x over previous
//
#include <hip/hip_runtime.h>

typedef unsigned int u32;
typedef _Float16 f16x8  __attribute__((ext_vector_type(8)));
typedef float    f32x16 __attribute__((ext_vector_type(16)));
typedef _Float16 v2h  __attribute__((ext_vector_type(2)));
typedef __fp16   v2fp __attribute__((ext_vector_type(2)));

#define E_TOT 160000
#define TPB   256
#define NBLK  1250        // 128 edges per block, BOTH classes per block
#define ASTR  20          // arena stride (u32) per edge slot; 16 used, 20 spreads banks

// ================= ws layout (u32) =================
// pair bases: p00=0, p10=2048, p01=4096, p11=6144
//   per pair: W1A[32 rows][16u32]@+0 | W2A[32][16]@+512 | W3A[M'][16]@+1024
//   rows are OUTPUT dims; 16 u32 = 32 f16, k ascending in pairs (2s,2s+1).
//   W1A row o: k<17 -> w1[k][o]; k==17 -> b1[o]; k>17 -> 0   (bias via x[17]=1)
//   W3A rows PERMUTED: nf=1 pairs: row' = i*8+o  (orig col o*8+i, M'=64)
//                      p11:        row' = (i*3+f)*8+o (orig col o*24+i*3+f, M'=192)
// bias region (f16 pairs, linear feat order): b2h[16] | b3h[M'/2] per pair:
//   p00@10240, p10@10288, p01@10336, p11@10384(b2) 10400(b3) .. 10496
// total 10496 u32 = 42 KB
// MFMA orientation: D[out][edge] = A(W, M=out rows) x B(acts, N=edges).
// Verified C/D map: col=lane&31 (edge), row=(reg&3)+8*(reg>>2)+4*(lane>>5).
// A/B k-slot convention (self-consistent, hw-map-independent): elem j <-> k=8*hi+j
// per 16-k step kk (k = 16*kk + 8*hi + j).

#define MFMA(a,b,c) __builtin_amdgcn_mfma_f32_32x32x16_f16((a),(b),(c),0,0,0)

__device__ __forceinline__ u32 pkh(float a, float b){
  union { v2fp h; u32 x; } u;
  u.h = __builtin_amdgcn_cvt_pkrtz(a, b);
  return u.x;
}
__device__ __forceinline__ v2h asvh(u32 x){
  union { u32 x; v2h h; } u; u.x = x; return u.h;
}

struct WPtrs { const float* p[24]; };  // (0,0),(1,0),(0,1),(1,1) x {w1,b1,w2,b2,w3,b3}

__global__ __launch_bounds__(256) void prep_kernel(WPtrs S, u32* __restrict__ ws)
{
  const int t = blockIdx.x*256 + threadIdx.x;
  if (t >= 10496) return;
  float a = 0.f, b = 0.f;
  if (t < 10240){
    const int pair = (t < 6144) ? (t >> 11) : 3;
    const int rel  = t - ((pair < 3) ? (pair << 11) : 6144);
    const float* __restrict__ w1 = S.p[pair*6+0];
    const float* __restrict__ b1 = S.p[pair*6+1];
    const float* __restrict__ w2 = S.p[pair*6+2];
    const float* __restrict__ w3 = S.p[pair*6+4];
    const int N3  = (pair < 3) ? 8  : 24;
    const int NC3 = (pair < 3) ? 64 : 192;
    if (rel < 512){                         // W1A
      int o = rel >> 4, k0 = (rel & 15)*2;
      a = (k0   < 17) ? w1[k0*32 + o]     : ((k0   == 17) ? b1[o] : 0.f);
      b = (k0+1 < 17) ? w1[(k0+1)*32 + o] : ((k0+1 == 17) ? b1[o] : 0.f);
    } else if (rel < 1024){                 // W2A
      int j = rel - 512; int o = j >> 4, k0 = (j & 15)*2;
      a = w2[k0*32 + o]; b = w2[(k0+1)*32 + o];
    } else {                                // W3A (row-permuted)
      int j = rel - 1024; int rp = j >> 4, k0 = (j & 15)*2;
      int col = (rp & 7)*N3 + (rp >> 3);
      a = w3[k0*NC3 + col]; b = w3[(k0+1)*NC3 + col];
    }
  } else {                                  // bias region
    const int rel  = t - 10240;
    const int pair = (rel < 144) ? (rel / 48) : 3;
    const int r2   = rel - ((pair < 3) ? pair*48 : 144);
    const float* __restrict__ b2 = S.p[pair*6+3];
    const float* __restrict__ b3 = S.p[pair*6+5];
    const int N3 = (pair < 3) ? 8 : 24;
    if (r2 < 16){ a = b2[2*r2]; b = b2[2*r2+1]; }
    else {
      int r0 = (r2-16)*2, r1 = r0+1;        // permuted rows
      a = b3[(r0 & 7)*N3 + (r0 >> 3)];
      b = b3[(r1 & 7)*N3 + (r1 >> 3)];
    }
  }
  ws[t] = pkh(a, b);
}

// ---- fragment helpers ----
__device__ __forceinline__ f16x8 ldfrag(const u32* __restrict__ p){   // global dwordx4
  union { uint4 u; f16x8 h; } c;
  c.u = *(const uint4*)p;
  return c.h;
}
__device__ __forceinline__ f16x8 ldB(const u32* AS, int hi, int kk){  // arena b128
  union { uint4 u; f16x8 h; } c;
  c.u = *(const uint4*)(AS + 8*kk + 4*hi);
  return c.h;
}
// relu + f16-pack C-frag -> arena (feat pair (8q+4hi.. ) -> slot 4q+2hi)
__device__ __forceinline__ void packH(u32* AS, int hi, const f32x16& c){
  #pragma unroll
  for (int q = 0; q < 4; ++q){
    u32 ua = pkh(fmaxf(c[4*q+0],0.f), fmaxf(c[4*q+1],0.f));
    u32 ub = pkh(fmaxf(c[4*q+2],0.f), fmaxf(c[4*q+3],0.f));
    *(uint2*)(AS + 4*q + 2*hi) = make_uint2(ua, ub);                  // ds_write_b64
  }
}
// C-init from f16 bias row block m (rows m*32 + 8q+4hi+0..3)
__device__ __forceinline__ f32x16 ldbias(const u32* __restrict__ ws, int base, int m, int hi){
  f32x16 c;
  #pragma unroll
  for (int q = 0; q < 4; ++q){
    uint2 v = *(const uint2*)(ws + base + m*16 + 4*q + 2*hi);
    v2h lo = asvh(v.x), hh = asvh(v.y);
    c[4*q+0] = (float)lo[0]; c[4*q+1] = (float)lo[1];
    c[4*q+2] = (float)hh[0]; c[4*q+3] = (float)hh[1];
  }
  return c;
}

// L1+L2 for one pair: bx frags -> H2 (f16) in arena. Bias b1 via k17, b2 via C-init.
__device__ __forceinline__ void mlp12(const u32* __restrict__ ws, int pb, int b2base,
                                      int row, int hi, f16x8 bx0, f16x8 bx1, u32* AS)
{
  const u32* W = ws + pb + row*16 + hi*4;
  f32x16 c;
  #pragma unroll
  for (int i = 0; i < 16; ++i) c[i] = 0.f;
  c = MFMA(ldfrag(W),     bx0, c);
  c = MFMA(ldfrag(W + 8), bx1, c);
  packH(AS, hi, c);                       // H1
  f16x8 h0 = ldB(AS, hi, 0), h1 = ldB(AS, hi, 1);
  f32x16 c2 = ldbias(ws, b2base, 0, hi);
  c2 = MFMA(ldfrag(W + 512),     h0, c2);
  c2 = MFMA(ldfrag(W + 512 + 8), h1, c2);
  packH(AS, hi, c2);                      // H2 (reads h0/h1 already in regs)
}

// L3 (M'=64, row'=i*8+o) + epilogue: acc[o'] += sum_i R[o'+4hi][i] * v[i]
__device__ __forceinline__ void l3acc(const u32* __restrict__ ws, int w3base, int b3base,
                                      int row, int hi, const u32* AS,
                                      const float (&v)[8], float (&acc)[4])
{
  f16x8 h0 = ldB(AS, hi, 0), h1 = ldB(AS, hi, 1);
  #pragma unroll
  for (int m = 0; m < 2; ++m){
    f32x16 c3 = ldbias(ws, b3base, m, hi);
    const u32* W = ws + w3base + (m*32 + row)*16 + hi*4;
    c3 = MFMA(ldfrag(W),     h0, c3);
    c3 = MFMA(ldfrag(W + 8), h1, c3);
    // value at reg r = R[o=(r&3)+4hi][i=4m+(r>>2)]  (row' = i*8+o check: =m*32+rowformula)
    #pragma unroll
    for (int r = 0; r < 16; ++r)
      acc[r & 3] = fmaf(c3[r], v[4*m + (r >> 2)], acc[r & 3]);
  }
}

__global__ __launch_bounds__(TPB, 2) void edge_kernel(
    const float* __restrict__ feat0, const float* __restrict__ feat1,
    const float* __restrict__ wE,    const float* __restrict__ radial,
    const float* __restrict__ b00,   const float* __restrict__ b01,
    const float* __restrict__ b10,   const float* __restrict__ b11,
    const int* __restrict__ src_idx, const u32* __restrict__ ws,
    float* __restrict__ out)
{
  __shared__ u32 XA[128 * ASTR];          // 10.2 KB, per-edge-slot, intra-wave only
  const int tid = threadIdx.x;
  const int w   = tid >> 6;
  const int hi  = (tid >> 5) & 1;
  const int row = tid & 31;               // = lane&31 = edge col / A-row
  const int e   = blockIdx.x*128 + w*32 + row;
  u32* AS = XA + (w*32 + row)*ASTR;
  const int idx = src_idx[e];

  // L1 B-frags (edge features), shared by all four pairs
  f16x8 bx0, bx1;
  {
    const float4* wp = (const float4*)(wE + (size_t)e*16 + 8*hi);
    float4 x0 = wp[0], x1 = wp[1];
    union { uint4 u; f16x8 h; } cc;
    cc.u = make_uint4(pkh(x0.x,x0.y), pkh(x0.z,x0.w), pkh(x1.x,x1.y), pkh(x1.z,x1.w));
    bx0 = cc.h;                           // k = 8hi..8hi+7
    cc.u = make_uint4(hi ? 0u : pkh(radial[e], 1.0f), 0u, 0u, 0u);
    bx1 = cc.h;                           // k16=radial, k17=1 (bias), rest 0
  }
  float f0v[8];
  {
    const float4* f = (const float4*)(feat0 + (size_t)idx*8);
    float4 u0 = f[0], u1 = f[1];
    f0v[0]=u0.x; f0v[1]=u0.y; f0v[2]=u0.z; f0v[3]=u0.w;
    f0v[4]=u1.x; f0v[5]=u1.y; f0v[6]=u1.z; f0v[7]=u1.w;
  }
  float f1v[24];
  {
    const float4* f = (const float4*)(feat1 + (size_t)idx*24);
    #pragma unroll
    for (int j = 0; j < 6; ++j){
      float4 v = f[j];
      f1v[4*j+0]=v.x; f1v[4*j+1]=v.y; f1v[4*j+2]=v.z; f1v[4*j+3]=v.w;
    }
  }
  const float bB = b00[e];
  float B10v[3], B01v[3];
  #pragma unroll
  for (int q = 0; q < 3; ++q){
    B10v[q] = b10[(size_t)e*3 + q];
    B01v[q] = b01[(size_t)e*3 + q];
  }
  float Uv[8];
  #pragma unroll
  for (int i = 0; i < 8; ++i)
    Uv[i] = fmaf(B10v[0], f1v[3*i], fmaf(B10v[1], f1v[3*i+1], B10v[2]*f1v[3*i+2]));

  // ================= class A: (0,0) + (1,0) -> out0 =================
  float mA[4] = {0.f, 0.f, 0.f, 0.f};
  mlp12(ws,    0, 10240, row, hi, bx0, bx1, AS);
  l3acc(ws, 1024, 10256, row, hi, AS, f0v, mA);
  #pragma unroll
  for (int j = 0; j < 4; ++j) mA[j] *= bB;        // basis_0_0 scalar
  mlp12(ws, 2048, 10288, row, hi, bx0, bx1, AS);
  l3acc(ws, 2048+1024, 10304, row, hi, AS, Uv, mA);
  // hi half owns o = 4hi..4hi+3 -> coalesced half-row store
  *(float4*)(out + (size_t)e*8 + 4*hi) = make_float4(mA[0], mA[1], mA[2], mA[3]);

  // ================= class B: (0,1) + (1,1) -> out1 =================
  float t01m[4] = {0.f, 0.f, 0.f, 0.f};
  mlp12(ws, 4096, 10336, row, hi, bx0, bx1, AS);
  l3acc(ws, 4096+1024, 10352, row, hi, AS, f0v, t01m);
  mlp12(ws, 6144, 10384, row, hi, bx0, bx1, AS); // (1,1) H2 -> arena
  float Bv[27];
  {
    const float* __restrict__ bp = b11 + (size_t)e*27;
    #pragma unroll
    for (int j = 0; j < 27; ++j) Bv[j] = bp[j];
  }
  float m1[12];
  #pragma unroll
  for (int o2 = 0; o2 < 4; ++o2)
    #pragma unroll
    for (int p = 0; p < 3; ++p)
      m1[o2*3+p] = t01m[o2] * B01v[p];
  {
    f16x8 h0 = ldB(AS, hi, 0), h1 = ldB(AS, hi, 1);
    #pragma unroll
    for (int m = 0; m < 6; ++m){          // 6 M-tiles of W3(1,1), row'=(i*3+f)*8+o
      f32x16 c3 = ldbias(ws, 10400, m, hi);
      const u32* W = ws + 7168 + (m*32 + row)*16 + hi*4;
      c3 = MFMA(ldfrag(W),     h0, c3);
      c3 = MFMA(ldfrag(W + 8), h1, c3);
      // reg r = R[o=(r&3)+4hi][ifp=4m+(r>>2)];  C1[ifp][p] = sum_q Bv[p,q,f]*s1[i,q]
      float C1[4][3];
      #pragma unroll
      for (int t2 = 0; t2 < 4; ++t2){
        const int ifp = 4*m + t2;
        const int ii = ifp / 3, ff = ifp - 3*ii;
        #pragma unroll
        for (int p = 0; p < 3; ++p)
          C1[t2][p] = fmaf(Bv[p*9 + 0 + ff], f1v[ii*3 + 0],
                      fmaf(Bv[p*9 + 3 + ff], f1v[ii*3 + 1],
                           Bv[p*9 + 6 + ff] * f1v[ii*3 + 2]));
      }
      #pragma unroll
      for (int r = 0; r < 16; ++r)
        #pragma unroll
        for (int p = 0; p < 3; ++p)
          m1[(r & 3)*3 + p] = fmaf(c3[r], C1[r >> 2][p], m1[(r & 3)*3 + p]);
    }
  }
  // hi half owns o = 4hi..4hi+3 -> 12 contiguous floats
  float* o1 = out + (size_t)E_TOT*8 + (size_t)e*24 + 12*hi;
  ((float4*)o1)[0] = make_float4(m1[0], m1[1], m1[2],  m1[3]);
  ((float4*)o1)[1] = make_float4(m1[4], m1[5], m1[6],  m1[7]);
  ((float4*)o1)[2] = make_float4(m1[8], m1[9], m1[10], m1[11]);
}

extern "C" void kernel_launch(void* const* d_in, const int* in_sizes, int n_in,
                              void* d_out, int out_size, void* d_ws, size_t ws_size,
                              hipStream_t stream)
{
  const float* feat0 = (const float*)d_in[0];
  const float* feat1 = (const float*)d_in[1];
  const float* wE    = (const float*)d_in[2];
  const float* rad   = (const float*)d_in[3];
  const float* b00   = (const float*)d_in[4];
  const float* b01   = (const float*)d_in[11];
  const float* b10   = (const float*)d_in[18];
  const float* b11   = (const float*)d_in[25];
  const int* sidx    = (const int*)d_in[32];
  u32* ws            = (u32*)d_ws;

  // ws pair order: (0,0), (1,0), (0,1), (1,1) -> d_in weight bases 5, 19, 12, 26
  const int base[4] = {5, 19, 12, 26};
  WPtrs S;
  for (int p = 0; p < 4; ++p)
    for (int k = 0; k < 6; ++k)
      S.p[p*6 + k] = (const float*)d_in[base[p] + k];

  prep_kernel<<<41, 256, 0, stream>>>(S, ws);
  edge_kernel<<<NBLK, TPB, 0, stream>>>(feat0, feat1, wE, rad, b00, b01, b10, b11,
                                        sidx, ws, (float*)d_out);
}